// Round 2
// baseline (467.604 us; speedup 1.0000x reference)
//
#include <hip/hip_runtime.h>
#include <math.h>

#define T_DIM 2048
#define B_DIM 16
#define M_DIM 512
#define H_DIM 256
#define N_ROWS (T_DIM * B_DIM)   // 32768
#define KC 512                   // concatenated re/im dim
#define CHUNK 64
#define NCHUNK (T_DIM / CHUNK)   // 32

// ---- workspace layout (float offsets) ----
#define WS_LAM   0                               // 512: lam_re[0..255], lam_im[256..511]
#define WS_LAML  512                             // 512: lam^CHUNK re/im
#define WS_WB    1024                            // 512*512: [Bnorm_re ; Bnorm_im][h][m]
#define WS_WC    (WS_WB + 262144)                // 512*512: Wc[m][k] = [C_re | -C_im]
#define WS_CARRY (WS_WC + 262144)                // 32*16*512
#define WS_BU    (WS_CARRY + NCHUNK * B_DIM * KC) // 32768*512 (Bu, then H in-place)

__global__ void prep_lam(const float* __restrict__ nu_log,
                         const float* __restrict__ theta_log,
                         float* __restrict__ ws) {
    int h = threadIdx.x;
    float nu = expf(nu_log[h]);
    float th = expf(theta_log[h]);
    float r  = expf(-nu);
    ws[WS_LAM + h]        = r * cosf(th);
    ws[WS_LAM + 256 + h]  = r * sinf(th);
    float rL  = expf(-64.f * nu);
    float thL = 64.f * th;
    ws[WS_LAML + h]       = rL * cosf(thL);
    ws[WS_LAML + 256 + h] = rL * sinf(thL);
}

__global__ void prep_w(const float* __restrict__ B_re, const float* __restrict__ B_im,
                       const float* __restrict__ gamma_log,
                       const float* __restrict__ C_re, const float* __restrict__ C_im,
                       float* __restrict__ ws) {
    int idx = blockIdx.x * blockDim.x + threadIdx.x;  // 0..262143
    int j = idx >> 9;       // row 0..511
    int m = idx & 511;      // col 0..511
    // Wb[j][m]: rows 0..255 = gamma*B_re, rows 256..511 = gamma*B_im
    float wb;
    if (j < 256) wb = expf(gamma_log[j])       * B_re[j * 512 + m];
    else         wb = expf(gamma_log[j - 256]) * B_im[(j - 256) * 512 + m];
    ws[WS_WB + idx] = wb;
    // Wc[m2][k]: k<256 -> C_re[m2][k], k>=256 -> -C_im[m2][k-256]
    int m2 = j, k = m;
    float wc;
    if (k < 256) wc =  C_re[m2 * 256 + k];
    else         wc = -C_im[m2 * 256 + (k - 256)];
    ws[WS_WC + idx] = wc;
}

// NT GEMM: Cout[n][j] = sum_k A[n][k] * W[j][k], K=512, cols=512.
// Tile 128x128, 256 threads, 8x8 microtile. Optional epilogue += Dv[col]*X[row][col].
template <int EPI>
__global__ __launch_bounds__(256) void gemm_nt(
    const float* __restrict__ A, const float* __restrict__ W,
    float* __restrict__ Cout, const float* __restrict__ Dv,
    const float* __restrict__ X) {
    __shared__ __align__(16) float As[16][132];
    __shared__ __align__(16) float Bs[16][132];
    const int bm = blockIdx.y << 7;
    const int bn = blockIdx.x << 7;
    const int tid = threadIdx.x;
    const int tx = tid & 15, ty = tid >> 4;

    float acc[8][8];
#pragma unroll
    for (int i = 0; i < 8; ++i)
#pragma unroll
        for (int j = 0; j < 8; ++j) acc[i][j] = 0.f;

    const int lrow = tid >> 2;        // 0..63
    const int lk = (tid & 3) << 2;    // 0,4,8,12

    for (int k0 = 0; k0 < 512; k0 += 16) {
#pragma unroll
        for (int p = 0; p < 2; ++p) {
            int row = (p << 6) + lrow;
            float4 va = *(const float4*)(&A[(size_t)(bm + row) * 512 + k0 + lk]);
            float4 vb = *(const float4*)(&W[(size_t)(bn + row) * 512 + k0 + lk]);
            As[lk + 0][row] = va.x; As[lk + 1][row] = va.y;
            As[lk + 2][row] = va.z; As[lk + 3][row] = va.w;
            Bs[lk + 0][row] = vb.x; Bs[lk + 1][row] = vb.y;
            Bs[lk + 2][row] = vb.z; Bs[lk + 3][row] = vb.w;
        }
        __syncthreads();
#pragma unroll
        for (int k = 0; k < 16; ++k) {
            float4 a0 = *(const float4*)(&As[k][ty << 3]);
            float4 a1 = *(const float4*)(&As[k][(ty << 3) + 4]);
            float4 b0 = *(const float4*)(&Bs[k][tx << 3]);
            float4 b1 = *(const float4*)(&Bs[k][(tx << 3) + 4]);
            float av[8] = {a0.x, a0.y, a0.z, a0.w, a1.x, a1.y, a1.z, a1.w};
            float bv[8] = {b0.x, b0.y, b0.z, b0.w, b1.x, b1.y, b1.z, b1.w};
#pragma unroll
            for (int i = 0; i < 8; ++i)
#pragma unroll
                for (int j = 0; j < 8; ++j)
                    acc[i][j] = fmaf(av[i], bv[j], acc[i][j]);
        }
        __syncthreads();
    }

#pragma unroll
    for (int i = 0; i < 8; ++i) {
        int row = bm + (ty << 3) + i;
        size_t rb = (size_t)row * 512;
#pragma unroll
        for (int j = 0; j < 8; j += 4) {
            int col = bn + (tx << 3) + j;
            float4 v = make_float4(acc[i][j], acc[i][j + 1], acc[i][j + 2], acc[i][j + 3]);
            if (EPI) {
                v.x += Dv[col + 0] * X[rb + col + 0];
                v.y += Dv[col + 1] * X[rb + col + 1];
                v.z += Dv[col + 2] * X[rb + col + 2];
                v.w += Dv[col + 3] * X[rb + col + 3];
            }
            *(float4*)(&Cout[rb + col]) = v;
        }
    }
}

// Pass A: per (chunk c, batch b, state h): local scan with zero init, store end value.
__global__ __launch_bounds__(256) void scan_local(float* __restrict__ ws) {
    const int c = blockIdx.x >> 4;
    const int b = blockIdx.x & 15;
    const int h = threadIdx.x;
    const float lr = ws[WS_LAM + h], li = ws[WS_LAM + 256 + h];
    const float* Bu = ws + WS_BU;
    float hr = 0.f, hi = 0.f;
    const int t0 = c * CHUNK;
    for (int l = 0; l < CHUNK; ++l) {
        size_t idx = ((size_t)(t0 + l) * B_DIM + b) * KC + h;
        float br = Bu[idx], bi = Bu[idx + 256];
        float nr = fmaf(lr, hr, fmaf(-li, hi, br));
        float ni = fmaf(lr, hi, fmaf(li, hr, bi));
        hr = nr; hi = ni;
    }
    size_t cidx = ((size_t)(c * B_DIM + b)) * KC + h;
    ws[WS_CARRY + cidx]       = hr;
    ws[WS_CARRY + cidx + 256] = hi;
}

// Pass B: sequential over 32 chunk aggregates per (b,h); turns carry[] into
// per-chunk carry-in states; final state = h_final -> write to d_out tail.
// h_final layout in d_out: PLANAR — re block [B*H] at base, im block [B*H]
// at base+4096 (im writes guarded by out_size in case harness dropped imag).
__global__ __launch_bounds__(256) void scan_carry(float* __restrict__ ws,
        const float* __restrict__ h_re, const float* __restrict__ h_im,
        float* __restrict__ out, int out_size) {
    const int b = blockIdx.x;
    const int h = threadIdx.x;
    const float Lr = ws[WS_LAML + h], Li = ws[WS_LAML + 256 + h];
    float cr = h_re[b * H_DIM + h], ci = h_im[b * H_DIM + h];
    for (int c = 0; c < NCHUNK; ++c) {
        size_t cidx = ((size_t)(c * B_DIM + b)) * KC + h;
        float sr = ws[WS_CARRY + cidx], si = ws[WS_CARRY + cidx + 256];
        ws[WS_CARRY + cidx]       = cr;
        ws[WS_CARRY + cidx + 256] = ci;
        float nr = fmaf(Lr, cr, fmaf(-Li, ci, sr));
        float ni = fmaf(Lr, ci, fmaf(Li, cr, si));
        cr = nr; ci = ni;
    }
    const size_t base = (size_t)T_DIM * B_DIM * M_DIM;   // 16777216
    const size_t idx  = (size_t)b * H_DIM + h;           // 0..4095
    size_t ore = base + idx;
    size_t oim = base + (size_t)B_DIM * H_DIM + idx;
    if (ore < (size_t)out_size) out[ore] = cr;
    if (oim < (size_t)out_size) out[oim] = ci;
}

// Pass C: replay each chunk from its carry-in, overwrite Bu with h_t in place.
__global__ __launch_bounds__(256) void scan_apply(float* __restrict__ ws) {
    const int c = blockIdx.x >> 4;
    const int b = blockIdx.x & 15;
    const int h = threadIdx.x;
    const float lr = ws[WS_LAM + h], li = ws[WS_LAM + 256 + h];
    float* Bu = ws + WS_BU;
    size_t cidx = ((size_t)(c * B_DIM + b)) * KC + h;
    float hr = ws[WS_CARRY + cidx], hi = ws[WS_CARRY + cidx + 256];
    const int t0 = c * CHUNK;
    for (int l = 0; l < CHUNK; ++l) {
        size_t idx = ((size_t)(t0 + l) * B_DIM + b) * KC + h;
        float br = Bu[idx], bi = Bu[idx + 256];
        float nr = fmaf(lr, hr, fmaf(-li, hi, br));
        float ni = fmaf(lr, hi, fmaf(li, hr, bi));
        hr = nr; hi = ni;
        Bu[idx] = hr; Bu[idx + 256] = hi;
    }
}

extern "C" void kernel_launch(void* const* d_in, const int* in_sizes, int n_in,
                              void* d_out, int out_size, void* d_ws, size_t ws_size,
                              hipStream_t stream) {
    const float* inputs    = (const float*)d_in[0];
    const float* h_re      = (const float*)d_in[1];
    const float* h_im      = (const float*)d_in[2];
    const float* nu_log    = (const float*)d_in[3];
    const float* theta_log = (const float*)d_in[4];
    const float* gamma_log = (const float*)d_in[5];
    const float* B_re      = (const float*)d_in[6];
    const float* B_im      = (const float*)d_in[7];
    const float* C_re      = (const float*)d_in[8];
    const float* C_im      = (const float*)d_in[9];
    const float* Dv        = (const float*)d_in[10];
    float* out = (float*)d_out;
    float* ws  = (float*)d_ws;

    prep_lam<<<1, 256, 0, stream>>>(nu_log, theta_log, ws);
    prep_w<<<1024, 256, 0, stream>>>(B_re, B_im, gamma_log, C_re, C_im, ws);

    // GEMM1: Bu[n][j] = X[n][:] . Wb[j][:]
    gemm_nt<0><<<dim3(4, 256), 256, 0, stream>>>(inputs, ws + WS_WB, ws + WS_BU,
                                                 nullptr, nullptr);

    scan_local<<<NCHUNK * B_DIM, 256, 0, stream>>>(ws);
    scan_carry<<<B_DIM, 256, 0, stream>>>(ws, h_re, h_im, out, out_size);
    scan_apply<<<NCHUNK * B_DIM, 256, 0, stream>>>(ws);

    // GEMM2: Y[n][m] = H[n][:] . Wc[m][:] + D[m]*X[n][m]
    gemm_nt<1><<<dim3(4, 256), 256, 0, stream>>>(ws + WS_BU, ws + WS_WC, out,
                                                 Dv, inputs);
}

// Round 3
// 153.522 us; speedup vs baseline: 3.0458x; 3.0458x over previous
//
#include <hip/hip_runtime.h>
#include <hip/hip_bf16.h>
#include <math.h>

#define T_DIM 2048
#define B_DIM 16
#define M_DIM 512
#define H_DIM 256
#define KC 512                   // concatenated re/im dim
#define K_DIM 512
#define CHUNK 64
#define NCHUNK (T_DIM / CHUNK)   // 32
#define BK 32

typedef unsigned short ushort_t;
typedef __attribute__((ext_vector_type(8))) short short8;
typedef __attribute__((ext_vector_type(8))) unsigned short ushort8;
typedef __attribute__((ext_vector_type(4))) float f32x4;

// ---- workspace layout (float offsets) ----
#define WS_LAM   0                // 512
#define WS_LAML  512              // 512
#define WS_CARRY 1024             // 32*16*512 = 262144
#define WS_WB_BF 263168           // 262144 ushort = 131072 floats
#define WS_WC_BF 394240           // 131072 floats
#define WS_BU    525312           // 32768*512 floats (Bu, then H in-place)

__device__ inline ushort_t f2bf(float f) {
    __hip_bfloat16 h = __float2bfloat16(f);
    return *reinterpret_cast<ushort_t*>(&h);
}

__global__ void prep_lam(const float* __restrict__ nu_log,
                         const float* __restrict__ theta_log,
                         float* __restrict__ ws) {
    int h = threadIdx.x;
    float nu = expf(nu_log[h]);
    float th = expf(theta_log[h]);
    float r  = expf(-nu);
    ws[WS_LAM + h]        = r * cosf(th);
    ws[WS_LAM + 256 + h]  = r * sinf(th);
    float rL  = expf(-64.f * nu);
    float thL = 64.f * th;
    ws[WS_LAML + h]       = rL * cosf(thL);
    ws[WS_LAML + 256 + h] = rL * sinf(thL);
}

// Build bf16 weights: Wb[j][m] (j: 0..255 = gamma*B_re, 256..511 = gamma*B_im),
// Wc[m][k] = [C_re | -C_im].
__global__ void prep_w(const float* __restrict__ B_re, const float* __restrict__ B_im,
                       const float* __restrict__ gamma_log,
                       const float* __restrict__ C_re, const float* __restrict__ C_im,
                       ushort_t* __restrict__ wb, ushort_t* __restrict__ wc) {
    int idx = blockIdx.x * blockDim.x + threadIdx.x;  // 0..262143
    int j = idx >> 9;
    int m = idx & 511;
    float v;
    if (j < 256) v = expf(gamma_log[j])       * B_re[j * 512 + m];
    else         v = expf(gamma_log[j - 256]) * B_im[(j - 256) * 512 + m];
    wb[idx] = f2bf(v);
    int m2 = j, k = m;
    float w;
    if (k < 256) w =  C_re[m2 * 256 + k];
    else         w = -C_im[m2 * 256 + (k - 256)];
    wc[idx] = f2bf(w);
}

// NT GEMM via MFMA bf16: Cout[n][j] = sum_k A[n][k]*W[j][k]; A fp32 reg-staged
// to bf16 LDS, W bf16 via global_load_lds(16B). Tile 128x128, BK=32, 4 waves,
// each wave 64x64 = 4x4 fragments of 16x16x32.
template <int EPI>
__global__ __launch_bounds__(256) void gemm_bf16(
    const float* __restrict__ A, const ushort_t* __restrict__ W,
    float* __restrict__ Cout, const float* __restrict__ Dv,
    const float* __restrict__ X) {
    __shared__ ushort_t Asl[128 * BK];   // row-major [128][32] bf16, 8KB
    __shared__ ushort_t Bsl[128 * BK];
    const int tid = threadIdx.x;
    const int bm = blockIdx.y << 7;
    const int bn = blockIdx.x << 7;
    const int lane = tid & 63;
    const int wid  = tid >> 6;
    const int wr = (wid >> 1) << 6;      // 0 / 64
    const int wc = (wid & 1) << 6;
    const int l16 = lane & 15;
    const int lk8 = (lane >> 4) << 3;    // 0,8,16,24

    f32x4 acc[4][4] = {};

    // staging chunk map: chunk c covers LDS ushorts [c*8, c*8+8); row=c>>2, sub=(c&3)*8
    const int c0 = tid, c1 = tid + 256;
    const int r0 = c0 >> 2, s0 = (c0 & 3) << 3;
    const int r1 = c1 >> 2, s1 = (c1 & 3) << 3;

    for (int k0 = 0; k0 < K_DIM; k0 += BK) {
        // B: async global->LDS, 16B per lane, linear dest
        __builtin_amdgcn_global_load_lds(
            (const __attribute__((address_space(1))) void*)(W + (size_t)(bn + r0) * K_DIM + k0 + s0),
            (__attribute__((address_space(3))) void*)(&Bsl[c0 * 8]), 16, 0, 0);
        __builtin_amdgcn_global_load_lds(
            (const __attribute__((address_space(1))) void*)(W + (size_t)(bn + r1) * K_DIM + k0 + s1),
            (__attribute__((address_space(3))) void*)(&Bsl[c1 * 8]), 16, 0, 0);
        // A: fp32 -> bf16 reg staging
        const float* a0p = &A[(size_t)(bm + r0) * K_DIM + k0 + s0];
        const float* a1p = &A[(size_t)(bm + r1) * K_DIM + k0 + s1];
        float4 va = *(const float4*)(a0p);
        float4 vb = *(const float4*)(a0p + 4);
        float4 vc = *(const float4*)(a1p);
        float4 vd = *(const float4*)(a1p + 4);
        ushort8 u0, u1;
        u0[0] = f2bf(va.x); u0[1] = f2bf(va.y); u0[2] = f2bf(va.z); u0[3] = f2bf(va.w);
        u0[4] = f2bf(vb.x); u0[5] = f2bf(vb.y); u0[6] = f2bf(vb.z); u0[7] = f2bf(vb.w);
        u1[0] = f2bf(vc.x); u1[1] = f2bf(vc.y); u1[2] = f2bf(vc.z); u1[3] = f2bf(vc.w);
        u1[4] = f2bf(vd.x); u1[5] = f2bf(vd.y); u1[6] = f2bf(vd.z); u1[7] = f2bf(vd.w);
        *(ushort8*)(&Asl[c0 * 8]) = u0;
        *(ushort8*)(&Asl[c1 * 8]) = u1;

        __syncthreads();   // drains vmcnt (gload_lds) + lgkm (ds_write)

        short8 af[4], bf[4];
#pragma unroll
        for (int m = 0; m < 4; ++m)
            af[m] = *(const short8*)(&Asl[(wr + m * 16 + l16) * BK + lk8]);
#pragma unroll
        for (int n = 0; n < 4; ++n)
            bf[n] = *(const short8*)(&Bsl[(wc + n * 16 + l16) * BK + lk8]);
#pragma unroll
        for (int m = 0; m < 4; ++m)
#pragma unroll
            for (int n = 0; n < 4; ++n)
                acc[m][n] = __builtin_amdgcn_mfma_f32_16x16x32_bf16(
                    af[m], bf[n], acc[m][n], 0, 0, 0);

        __syncthreads();
    }

    // epilogue: C/D layout col=lane&15, row=(lane>>4)*4+reg
    const int fr = (lane >> 4) << 2;
#pragma unroll
    for (int m = 0; m < 4; ++m) {
#pragma unroll
        for (int n = 0; n < 4; ++n) {
#pragma unroll
            for (int r = 0; r < 4; ++r) {
                int row = bm + wr + m * 16 + fr + r;
                int col = bn + wc + n * 16 + l16;
                float v = acc[m][n][r];
                size_t o = (size_t)row * 512 + col;
                if (EPI) v += Dv[col] * X[o];
                Cout[o] = v;
            }
        }
    }
}

// Pass A: per (chunk c, batch b, state h): local scan, zero init, store end value.
__global__ __launch_bounds__(256) void scan_local(float* __restrict__ ws) {
    const int c = blockIdx.x >> 4;
    const int b = blockIdx.x & 15;
    const int h = threadIdx.x;
    const float lr = ws[WS_LAM + h], li = ws[WS_LAM + 256 + h];
    const float* Bu = ws + WS_BU;
    float hr = 0.f, hi = 0.f;
    const int t0 = c * CHUNK;
    for (int l = 0; l < CHUNK; ++l) {
        size_t idx = ((size_t)(t0 + l) * B_DIM + b) * KC + h;
        float br = Bu[idx], bi = Bu[idx + 256];
        float nr = fmaf(lr, hr, fmaf(-li, hi, br));
        float ni = fmaf(lr, hi, fmaf(li, hr, bi));
        hr = nr; hi = ni;
    }
    size_t cidx = ((size_t)(c * B_DIM + b)) * KC + h;
    ws[WS_CARRY + cidx]       = hr;
    ws[WS_CARRY + cidx + 256] = hi;
}

// Pass B: sequential over 32 chunk aggregates; h_final planar re/im to out tail.
__global__ __launch_bounds__(256) void scan_carry(float* __restrict__ ws,
        const float* __restrict__ h_re, const float* __restrict__ h_im,
        float* __restrict__ out, int out_size) {
    const int b = blockIdx.x;
    const int h = threadIdx.x;
    const float Lr = ws[WS_LAML + h], Li = ws[WS_LAML + 256 + h];
    float cr = h_re[b * H_DIM + h], ci = h_im[b * H_DIM + h];
    for (int c = 0; c < NCHUNK; ++c) {
        size_t cidx = ((size_t)(c * B_DIM + b)) * KC + h;
        float sr = ws[WS_CARRY + cidx], si = ws[WS_CARRY + cidx + 256];
        ws[WS_CARRY + cidx]       = cr;
        ws[WS_CARRY + cidx + 256] = ci;
        float nr = fmaf(Lr, cr, fmaf(-Li, ci, sr));
        float ni = fmaf(Lr, ci, fmaf(Li, cr, si));
        cr = nr; ci = ni;
    }
    const size_t base = (size_t)T_DIM * B_DIM * M_DIM;
    const size_t idx  = (size_t)b * H_DIM + h;
    size_t ore = base + idx;
    size_t oim = base + (size_t)B_DIM * H_DIM + idx;
    if (ore < (size_t)out_size) out[ore] = cr;
    if (oim < (size_t)out_size) out[oim] = ci;
}

// Pass C: replay each chunk from carry-in, overwrite Bu with h_t in place (fp32).
__global__ __launch_bounds__(256) void scan_apply(float* __restrict__ ws) {
    const int c = blockIdx.x >> 4;
    const int b = blockIdx.x & 15;
    const int h = threadIdx.x;
    const float lr = ws[WS_LAM + h], li = ws[WS_LAM + 256 + h];
    float* Bu = ws + WS_BU;
    size_t cidx = ((size_t)(c * B_DIM + b)) * KC + h;
    float hr = ws[WS_CARRY + cidx], hi = ws[WS_CARRY + cidx + 256];
    const int t0 = c * CHUNK;
    for (int l = 0; l < CHUNK; ++l) {
        size_t idx = ((size_t)(t0 + l) * B_DIM + b) * KC + h;
        float br = Bu[idx], bi = Bu[idx + 256];
        float nr = fmaf(lr, hr, fmaf(-li, hi, br));
        float ni = fmaf(lr, hi, fmaf(li, hr, bi));
        hr = nr; hi = ni;
        Bu[idx] = hr; Bu[idx + 256] = hi;
    }
}

extern "C" void kernel_launch(void* const* d_in, const int* in_sizes, int n_in,
                              void* d_out, int out_size, void* d_ws, size_t ws_size,
                              hipStream_t stream) {
    const float* inputs    = (const float*)d_in[0];
    const float* h_re      = (const float*)d_in[1];
    const float* h_im      = (const float*)d_in[2];
    const float* nu_log    = (const float*)d_in[3];
    const float* theta_log = (const float*)d_in[4];
    const float* gamma_log = (const float*)d_in[5];
    const float* B_re      = (const float*)d_in[6];
    const float* B_im      = (const float*)d_in[7];
    const float* C_re      = (const float*)d_in[8];
    const float* C_im      = (const float*)d_in[9];
    const float* Dv        = (const float*)d_in[10];
    float* out = (float*)d_out;
    float* ws  = (float*)d_ws;
    ushort_t* wb = (ushort_t*)(ws + WS_WB_BF);
    ushort_t* wc = (ushort_t*)(ws + WS_WC_BF);

    prep_lam<<<1, 256, 0, stream>>>(nu_log, theta_log, ws);
    prep_w<<<1024, 256, 0, stream>>>(B_re, B_im, gamma_log, C_re, C_im, wb, wc);

    // GEMM1: Bu[n][j] = X[n][:] . Wb[j][:]
    gemm_bf16<0><<<dim3(4, 256), 256, 0, stream>>>(inputs, wb, ws + WS_BU,
                                                   nullptr, nullptr);

    scan_local<<<NCHUNK * B_DIM, 256, 0, stream>>>(ws);
    scan_carry<<<B_DIM, 256, 0, stream>>>(ws, h_re, h_im, out, out_size);
    scan_apply<<<NCHUNK * B_DIM, 256, 0, stream>>>(ws);

    // GEMM2: Y[n][m] = H[n][:] . Wc[m][:] + D[m]*X[n][m]
    gemm_bf16<1><<<dim3(4, 256), 256, 0, stream>>>(ws + WS_BU, wc, out,
                                                   Dv, inputs);
}

// Round 4
// 115.861 us; speedup vs baseline: 4.0359x; 1.3251x over previous
//
#include <hip/hip_runtime.h>
#include <hip/hip_bf16.h>
#include <math.h>

#define T_DIM 2048
#define B_DIM 16
#define M_DIM 512
#define H_DIM 256
#define KC 512
#define K_DIM 512
#define CHUNK 64
#define NCHUNK 32
#define BK 32
#define NT (K_DIM / BK)     // 16 k-tiles

typedef unsigned short ushort_t;
typedef __attribute__((ext_vector_type(8))) short short8;
typedef __attribute__((ext_vector_type(8))) unsigned short ushort8;
typedef __attribute__((ext_vector_type(4))) float f32x4;

// ---- workspace layout (float offsets) ----
#define WS_LAM   0                // 512
#define WS_LAML  512              // 512
#define WS_CARRY 1024             // 262144 floats
#define WS_WB_BF 263168           // 262144 ushorts (tiled, k-major)
#define WS_WC_BF 394240           // 262144 ushorts (tiled, k-major)
#define WS_BU    525312           // 16777216 ushorts (Bu, then H in place)

__device__ inline ushort_t f2bf(float f) {
    __hip_bfloat16 h = __float2bfloat16(f);
    return *reinterpret_cast<ushort_t*>(&h);
}
__device__ inline float bf2f(ushort_t u) {
    union { unsigned int i; float f; } v;
    v.i = ((unsigned int)u) << 16;
    return v.f;
}

__global__ void prep_lam(const float* __restrict__ nu_log,
                         const float* __restrict__ theta_log,
                         float* __restrict__ ws) {
    int h = threadIdx.x;
    float nu = expf(nu_log[h]);
    float th = expf(theta_log[h]);
    float r  = expf(-nu);
    ws[WS_LAM + h]        = r * cosf(th);
    ws[WS_LAM + 256 + h]  = r * sinf(th);
    float rL  = expf(-64.f * nu);
    float thL = 64.f * th;
    ws[WS_LAML + h]       = rL * cosf(thL);
    ws[WS_LAML + 256 + h] = rL * sinf(thL);
}

// bf16 weights pre-tiled for LDS-ready k-major staging:
// index = (((blk*NT + t)*4 + ks)*128 + row)*8 + e
//   maps to W[j = blk*128+row][k = t*32 + ks*8 + e]
__global__ void prep_w(const float* __restrict__ B_re, const float* __restrict__ B_im,
                       const float* __restrict__ gamma_log,
                       const float* __restrict__ C_re, const float* __restrict__ C_im,
                       ushort_t* __restrict__ wb, ushort_t* __restrict__ wc) {
    int idx = blockIdx.x * blockDim.x + threadIdx.x;  // 0..262143
    int e    = idx & 7;
    int slot = (idx >> 3) & 511;
    int row  = slot & 127;
    int ks   = slot >> 7;
    int t    = (idx >> 12) & 15;
    int blk  = idx >> 16;
    int j = blk * 128 + row;
    int k = t * 32 + ks * 8 + e;
    float v;
    if (j < 256) v = expf(gamma_log[j])       * B_re[j * 512 + k];
    else         v = expf(gamma_log[j - 256]) * B_im[(j - 256) * 512 + k];
    wb[idx] = f2bf(v);
    float w;
    if (k < 256) w =  C_re[j * 256 + k];
    else         w = -C_im[j * 256 + (k - 256)];
    wc[idx] = f2bf(w);
}

// NT GEMM via MFMA bf16, double-buffered LDS, k-major conflict-free layout.
// A_BF16: A operand is bf16 in memory (else fp32, reg-staged + cvt).
// OUT_BF16: write bf16 output (Bu); else fp32 output with +D*X epilogue.
template <int A_BF16, int OUT_BF16>
__global__ __launch_bounds__(256) void gemm_mfma(
    const void* __restrict__ Aptr, const ushort_t* __restrict__ Wt,
    void* __restrict__ Cv, const float* __restrict__ Dv,
    const float* __restrict__ X) {
    __shared__ ushort_t Asl[2][4096];   // 2 x 8KB, slots: ks*128+row, 8 ushorts each
    __shared__ ushort_t Bsl[2][4096];
    const int tid = threadIdx.x;
    const int bm = blockIdx.x << 7;     // row tile (x fastest -> A-panel shares XCD)
    const int bnb = blockIdx.y;         // col tile 0..3
    const int bn = bnb << 7;
    const int lane = tid & 63;
    const int wid  = tid >> 6;
    const int wr  = (wid >> 1) << 6;
    const int wcc = (wid & 1) << 6;
    const int l16 = lane & 15;
    const int ksl = lane >> 4;          // frag k-slot 0..3

    // B staging: linear dest slot c = tid / tid+256, source pre-tiled => coalesced
    const int c0 = tid, c1 = tid + 256;
    // A staging: thread covers row=tid>>1, ks = {aks, aks+1}, 16 consecutive k
    const int arow = tid >> 1;
    const int aks  = (tid & 1) << 1;
    const int as0  = (aks * 128 + arow) * 8;
    const int as1  = as0 + 1024;        // +128 slots

    const float*    Af = (const float*)Aptr;
    const ushort_t* Ab = (const ushort_t*)Aptr;

    f32x4 acc[4][4] = {};
    float4 pva0, pva1, pvb0, pvb1;
    ushort8 pua0, pua1;

    auto stageB = [&](int t, int buf) {
        size_t base = ((size_t)(bnb * NT + t)) * 4096;
        __builtin_amdgcn_global_load_lds(
            (const __attribute__((address_space(1))) void*)(Wt + base + c0 * 8),
            (__attribute__((address_space(3))) void*)(&Bsl[buf][c0 * 8]), 16, 0, 0);
        __builtin_amdgcn_global_load_lds(
            (const __attribute__((address_space(1))) void*)(Wt + base + c1 * 8),
            (__attribute__((address_space(3))) void*)(&Bsl[buf][c1 * 8]), 16, 0, 0);
    };
    auto loadA = [&](int t) {
        if constexpr (A_BF16) {
            const ushort_t* p = Ab + (size_t)(bm + arow) * K_DIM + t * BK + aks * 8;
            pua0 = *(const ushort8*)(p);
            pua1 = *(const ushort8*)(p + 8);
        } else {
            const float* p = Af + (size_t)(bm + arow) * K_DIM + t * BK + aks * 8;
            pva0 = *(const float4*)(p);
            pva1 = *(const float4*)(p + 4);
            pvb0 = *(const float4*)(p + 8);
            pvb1 = *(const float4*)(p + 12);
        }
    };
    auto writeA = [&](int buf) {
        ushort8 u0, u1;
        if constexpr (A_BF16) {
            u0 = pua0; u1 = pua1;
        } else {
            u0[0] = f2bf(pva0.x); u0[1] = f2bf(pva0.y); u0[2] = f2bf(pva0.z); u0[3] = f2bf(pva0.w);
            u0[4] = f2bf(pva1.x); u0[5] = f2bf(pva1.y); u0[6] = f2bf(pva1.z); u0[7] = f2bf(pva1.w);
            u1[0] = f2bf(pvb0.x); u1[1] = f2bf(pvb0.y); u1[2] = f2bf(pvb0.z); u1[3] = f2bf(pvb0.w);
            u1[4] = f2bf(pvb1.x); u1[5] = f2bf(pvb1.y); u1[6] = f2bf(pvb1.z); u1[7] = f2bf(pvb1.w);
        }
        *(ushort8*)(&Asl[buf][as0]) = u0;
        *(ushort8*)(&Asl[buf][as1]) = u1;
    };

    // prologue: stage tile 0 into buf 0
    stageB(0, 0);
    loadA(0);
    writeA(0);
    __syncthreads();

    int cur = 0;
#pragma unroll 2
    for (int t = 0; t < NT; ++t) {
        const int nxt = cur ^ 1;
        if (t + 1 < NT) { stageB(t + 1, nxt); loadA(t + 1); }
        short8 afr[4], bfr[4];
#pragma unroll
        for (int m = 0; m < 4; ++m)
            afr[m] = *(const short8*)(&Asl[cur][(ksl * 128 + wr + m * 16 + l16) * 8]);
#pragma unroll
        for (int n = 0; n < 4; ++n)
            bfr[n] = *(const short8*)(&Bsl[cur][(ksl * 128 + wcc + n * 16 + l16) * 8]);
#pragma unroll
        for (int m = 0; m < 4; ++m)
#pragma unroll
            for (int n = 0; n < 4; ++n)
                acc[m][n] = __builtin_amdgcn_mfma_f32_16x16x32_bf16(
                    afr[m], bfr[n], acc[m][n], 0, 0, 0);
        if (t + 1 < NT) writeA(nxt);
        __syncthreads();
        cur = nxt;
    }

    // epilogue: C/D layout col=lane&15, row=(lane>>4)*4+reg
    const int fr = (lane >> 4) << 2;
#pragma unroll
    for (int m = 0; m < 4; ++m) {
#pragma unroll
        for (int n = 0; n < 4; ++n) {
#pragma unroll
            for (int r = 0; r < 4; ++r) {
                int row = bm + wr + m * 16 + fr + r;
                int col = bn + wcc + n * 16 + l16;
                size_t o = (size_t)row * 512 + col;
                float v = acc[m][n][r];
                if constexpr (OUT_BF16) {
                    ((ushort_t*)Cv)[o] = f2bf(v);
                } else {
                    ((float*)Cv)[o] = v + Dv[col] * X[o];
                }
            }
        }
    }
}

// Pass A: per (chunk c, batch b, state h): local scan, zero init, store end value.
__global__ __launch_bounds__(256) void scan_local(float* __restrict__ ws) {
    const int c = blockIdx.x >> 4;
    const int b = blockIdx.x & 15;
    const int h = threadIdx.x;
    const float lr = ws[WS_LAM + h], li = ws[WS_LAM + 256 + h];
    const ushort_t* Bu = (const ushort_t*)(ws + WS_BU);
    float hr = 0.f, hi = 0.f;
    const int t0 = c * CHUNK;
    for (int l = 0; l < CHUNK; ++l) {
        size_t idx = ((size_t)(t0 + l) * B_DIM + b) * KC + h;
        float br = bf2f(Bu[idx]), bi = bf2f(Bu[idx + 256]);
        float nr = fmaf(lr, hr, fmaf(-li, hi, br));
        float ni = fmaf(lr, hi, fmaf(li, hr, bi));
        hr = nr; hi = ni;
    }
    size_t cidx = ((size_t)(c * B_DIM + b)) * KC + h;
    ws[WS_CARRY + cidx]       = hr;
    ws[WS_CARRY + cidx + 256] = hi;
}

// Pass B: sequential over 32 chunk aggregates; h_final planar re/im to out tail.
__global__ __launch_bounds__(256) void scan_carry(float* __restrict__ ws,
        const float* __restrict__ h_re, const float* __restrict__ h_im,
        float* __restrict__ out, int out_size) {
    const int b = blockIdx.x;
    const int h = threadIdx.x;
    const float Lr = ws[WS_LAML + h], Li = ws[WS_LAML + 256 + h];
    float cr = h_re[b * H_DIM + h], ci = h_im[b * H_DIM + h];
    for (int c = 0; c < NCHUNK; ++c) {
        size_t cidx = ((size_t)(c * B_DIM + b)) * KC + h;
        float sr = ws[WS_CARRY + cidx], si = ws[WS_CARRY + cidx + 256];
        ws[WS_CARRY + cidx]       = cr;
        ws[WS_CARRY + cidx + 256] = ci;
        float nr = fmaf(Lr, cr, fmaf(-Li, ci, sr));
        float ni = fmaf(Lr, ci, fmaf(Li, cr, si));
        cr = nr; ci = ni;
    }
    const size_t base = (size_t)T_DIM * B_DIM * M_DIM;
    const size_t idx  = (size_t)b * H_DIM + h;
    size_t ore = base + idx;
    size_t oim = base + (size_t)B_DIM * H_DIM + idx;
    if (ore < (size_t)out_size) out[ore] = cr;
    if (oim < (size_t)out_size) out[oim] = ci;
}

// Pass C: replay each chunk from carry-in; overwrite Bu with h_t (bf16) in place.
__global__ __launch_bounds__(256) void scan_apply(float* __restrict__ ws) {
    const int c = blockIdx.x >> 4;
    const int b = blockIdx.x & 15;
    const int h = threadIdx.x;
    const float lr = ws[WS_LAM + h], li = ws[WS_LAM + 256 + h];
    ushort_t* Bu = (ushort_t*)(ws + WS_BU);
    size_t cidx = ((size_t)(c * B_DIM + b)) * KC + h;
    float hr = ws[WS_CARRY + cidx], hi = ws[WS_CARRY + cidx + 256];
    const int t0 = c * CHUNK;
    for (int l = 0; l < CHUNK; ++l) {
        size_t idx = ((size_t)(t0 + l) * B_DIM + b) * KC + h;
        float br = bf2f(Bu[idx]), bi = bf2f(Bu[idx + 256]);
        float nr = fmaf(lr, hr, fmaf(-li, hi, br));
        float ni = fmaf(lr, hi, fmaf(li, hr, bi));
        hr = nr; hi = ni;
        Bu[idx]       = f2bf(hr);
        Bu[idx + 256] = f2bf(hi);
    }
}

extern "C" void kernel_launch(void* const* d_in, const int* in_sizes, int n_in,
                              void* d_out, int out_size, void* d_ws, size_t ws_size,
                              hipStream_t stream) {
    const float* inputs    = (const float*)d_in[0];
    const float* h_re      = (const float*)d_in[1];
    const float* h_im      = (const float*)d_in[2];
    const float* nu_log    = (const float*)d_in[3];
    const float* theta_log = (const float*)d_in[4];
    const float* gamma_log = (const float*)d_in[5];
    const float* B_re      = (const float*)d_in[6];
    const float* B_im      = (const float*)d_in[7];
    const float* C_re      = (const float*)d_in[8];
    const float* C_im      = (const float*)d_in[9];
    const float* Dv        = (const float*)d_in[10];
    float* out = (float*)d_out;
    float* ws  = (float*)d_ws;
    ushort_t* wb = (ushort_t*)(ws + WS_WB_BF);
    ushort_t* wc = (ushort_t*)(ws + WS_WC_BF);
    ushort_t* bu = (ushort_t*)(ws + WS_BU);

    prep_lam<<<1, 256, 0, stream>>>(nu_log, theta_log, ws);
    prep_w<<<1024, 256, 0, stream>>>(B_re, B_im, gamma_log, C_re, C_im, wb, wc);

    // GEMM1: Bu[n][j] = X[n][:] . Wb[j][:]  (fp32 A, bf16 out)
    gemm_mfma<0, 1><<<dim3(256, 4), 256, 0, stream>>>(inputs, wb, (void*)bu,
                                                      nullptr, nullptr);

    scan_local<<<NCHUNK * B_DIM, 256, 0, stream>>>(ws);
    scan_carry<<<B_DIM, 256, 0, stream>>>(ws, h_re, h_im, out, out_size);
    scan_apply<<<NCHUNK * B_DIM, 256, 0, stream>>>(ws);

    // GEMM2: Y[n][m] = H[n][:] . Wc[m][:] + D[m]*X[n][m]  (bf16 A, fp32 out)
    gemm_mfma<1, 0><<<dim3(256, 4), 256, 0, stream>>>(bu, wc, (void*)out,
                                                      Dv, inputs);
}